// Round 1
// 104.802 us; speedup vs baseline: 1.0132x; 1.0132x over previous
//
#include <hip/hip_runtime.h>

// Viterbi trellis quantizer: S=1024 states, K=2 (4 predecessors), CHUNK=4,
// block_size=16 -> T=64 steps/chain, B=4096 chains (16x16 blocks of 1024^2).
//
// One 64-lane wave per chain. beta-formulation: beta[s] = -(alpha[s]-||x||^2)/2,
//   beta_new[s] = M[s>>2] + (cb[s]·x + h[s]),  h = -||cb||^2/2,
// with grouped max M[p] = max_j beta[p + 256 j] and 2-bit backpointers per
// group (decision for state s depends only on s>>2 -> 64 bytes/step).
//
// R3 changes (theory: VGPR_Count=60 < the 80 pinned codebook regs proves the
// allocator banked the codebook in AGPRs; granule-rounded total exceeded the
// 128-reg budget -> 3 waves/EU + a 1-block/CU tail on the 1024-block grid
// (measured 30% occupancy ~= 0.75*37.5 + 0.25*12), plus likely per-step
// v_accvgpr_read traffic explaining ~254 issued VALU/step vs ~124 in source):
//   1. 2 chains per 128-thread block (2048 blocks). Waves are fully
//      independent -> NO __syncthreads anywhere; tail granularity 2 waves.
//   2. Pin-asm removed. R2's spill happened when the allocator chased 8
//      waves/EU (64-reg budget); amdgpu_waves_per_eu(4,4) makes the budget an
//      honest 128 and demand is ~110, so clean arch-VGPR allocation is
//      cheapest. Tripwire if wrong: WRITE_SIZE jumps above 5120 KB.
//   3. 4-way max chained so clang emits v_max3_f32 + v_max_f32 (exact; tie
//      break still via first-==v chain, so absmax stays 0).

#define COLS      1024
#define T_STEPS   64
#define REC_SIZE  (1024 * 1024)

__global__ __launch_bounds__(128)
__attribute__((amdgpu_waves_per_eu(4, 4)))
void viterbi_q(
    const float* __restrict__ arr,
    const float* __restrict__ cbook,
    float* __restrict__ out)
{
    const int tid   = threadIdx.x;
    const int wid   = tid >> 6;      // chain slot in block (0..1)
    const int lane  = tid & 63;
    const int chain = (blockIdx.x << 1) | wid;   // 0..4095
    const int rb    = chain >> 6;    // block-row
    const int cb    = chain & 63;    // block-col

    __shared__ __align__(16) float tile[2][256];   // x chunks for the chain
    __shared__ __align__(16) float Mst[2][256];    // grouped-max state M[p]
    __shared__ unsigned char Jb[2][63 * 64];       // packed backpointers
    __shared__ int st_lds[2][64];                  // traced-back states

    // ---- stage this chain's 16x16 tile into LDS (tile[e], e = r*16 + c) ----
    {
        const int r  = lane >> 2;
        const int c4 = (lane & 3) << 2;
        float4 v = *(const float4*)(arr + (rb * 16 + r) * COLS + cb * 16 + c4);
        *(float4*)&tile[wid][lane << 2] = v;
    }
    // M starts at 0: iteration t=0 then computes beta0 = cb·x0 + h exactly.
    *(float4*)&Mst[wid][lane << 2] = make_float4(0.f, 0.f, 0.f, 0.f);

    // ---- codebook rows for this lane's 16 states: s = 4*lane + c + 256*j ----
    float4 a[16];   // raw codebook row
    float  h[16];   // -||row||^2 / 2
    #pragma unroll
    for (int j = 0; j < 4; ++j) {
        #pragma unroll
        for (int c = 0; c < 4; ++c) {
            const int row = (lane << 2) + c + (j << 8);
            float4 v = *(const float4*)(cbook + row * 4);
            a[j * 4 + c] = v;
            h[j * 4 + c] = -0.5f * (v.x * v.x + v.y * v.y +
                                    v.z * v.z + v.w * v.w);
        }
    }

    // hoisted LDS pointers
    const float* __restrict__ tilep = &tile[wid][0];
    float* __restrict__ Mp          = &Mst[wid][0];
    unsigned char* __restrict__ Jp  = &Jb[wid][0];

    // ---- forward recursion, t = 0..62: store backpointers J_t ----
    #pragma unroll 1
    for (int t = 0; t < T_STEPS - 1; ++t) {
        const float4 xt = *(const float4*)&tilep[t << 2];   // broadcast read
        float mj[4];
        #pragma unroll
        for (int j = 0; j < 4; ++j)
            mj[j] = Mp[lane + 64 * j];

        float nm[4];
        unsigned bp = 0;
        #pragma unroll
        for (int c = 0; c < 4; ++c) {
            float cand[4];
            #pragma unroll
            for (int j = 0; j < 4; ++j) {
                const float4 av = a[j * 4 + c];
                float acc = fmaf(av.x, xt.x, h[j * 4 + c]);
                acc = fmaf(av.y, xt.y, acc);
                acc = fmaf(av.z, xt.z, acc);
                acc = fmaf(av.w, xt.w, acc);
                cand[j] = acc + mj[j];
            }
            // chained shape -> v_max3_f32 + v_max_f32 (max is exact, any tree ok)
            const float v = fmaxf(fmaxf(fmaxf(cand[0], cand[1]), cand[2]),
                                  cand[3]);
            // first-max index == reference's first-min over alpha candidates
            const int j = (cand[0] == v) ? 0
                        : (cand[1] == v) ? 1
                        : (cand[2] == v) ? 2 : 3;
            nm[c] = v;
            bp |= (unsigned)j << (2 * c);
        }
        // wave-lockstep: all lanes issued their M reads above before this write
        *(float4*)&Mp[lane << 2] = make_float4(nm[0], nm[1], nm[2], nm[3]);
        Jp[t * 64 + lane] = (unsigned char)bp;
    }

    // ---- final step t = 63: full argmax over beta_63[0..1023] ----
    int bests;
    {
        const int t = T_STEPS - 1;
        const float4 xt = *(const float4*)&tilep[t << 2];
        float mj[4];
        #pragma unroll
        for (int j = 0; j < 4; ++j)
            mj[j] = Mp[lane + 64 * j];

        float bv = -3.4e38f;
        int   bs = 0;
        #pragma unroll
        for (int j = 0; j < 4; ++j) {      // s ascends with (j, c): first-max ok
            #pragma unroll
            for (int c = 0; c < 4; ++c) {
                const float4 av = a[j * 4 + c];
                float acc = fmaf(av.x, xt.x, h[j * 4 + c]);
                acc = fmaf(av.y, xt.y, acc);
                acc = fmaf(av.z, xt.z, acc);
                acc = fmaf(av.w, xt.w, acc);
                acc += mj[j];
                if (acc > bv) { bv = acc; bs = (lane << 2) + c + (j << 8); }
            }
        }
        // lexicographic (value desc, state asc) butterfly across the wave
        #pragma unroll
        for (int off = 32; off > 0; off >>= 1) {
            const float ov = __shfl_xor(bv, off, 64);
            const int   os = __shfl_xor(bs, off, 64);
            if (ov > bv || (ov == bv && os < bs)) { bv = ov; bs = os; }
        }
        bests = bs;
    }

    // ---- traceback (serial, lane 0 of each wave) ----
    if (lane == 0) {
        int s = bests;
        st_lds[wid][T_STEPS - 1] = s;
        for (int i = T_STEPS - 2; i >= 0; --i) {
            const int p = s >> 2;
            const unsigned byte = Jp[i * 64 + (p >> 2)];
            const int j = (byte >> (2 * (p & 3))) & 3;
            s = p + (j << 8);
            st_lds[wid][i] = s;
        }
    }
    // NO barrier: st_lds[wid] is written by lane 0 of THIS wave and read by
    // the same wave below; wave-lockstep + in-order LDS makes it visible.

    // ---- outputs: lane i handles step t = i ----
    const int st = st_lds[wid][lane];
    // states_out flat: REC_SIZE + chain*64 + t   (stored as float values)
    out[REC_SIZE + chain * 64 + lane] = (float)st;
    // rec: step t covers elements e = 4t..4t+3 -> row t>>2, cols 4*(t&3)..+3
    const float4 v = *(const float4*)(cbook + st * 4);
    const int r  = lane >> 2;
    const int c4 = (lane & 3) << 2;
    *(float4*)(out + (rb * 16 + r) * COLS + cb * 16 + c4) = v;
}

extern "C" void kernel_launch(void* const* d_in, const int* in_sizes, int n_in,
                              void* d_out, int out_size, void* d_ws, size_t ws_size,
                              hipStream_t stream)
{
    const float* arr   = (const float*)d_in[0];
    const float* cbook = (const float*)d_in[1];
    float* out = (float*)d_out;
    // 4096 chains, 2 chains (waves) per 128-thread block -> 2048 blocks
    viterbi_q<<<dim3(2048), dim3(128), 0, stream>>>(arr, cbook, out);
}